// Round 3
// baseline (390.845 us; speedup 1.0000x reference)
//
#include <hip/hip_runtime.h>
#include <math.h>

#define N_NODES 20000
#define N_EDGES 320000
#define DD 128
#define ND (N_NODES * DD)   // 2,560,000
#define ND4 (ND / 4)        // 640,000
#define NPG 2500            // nodes per graph
#define RED_BLOCKS 625

// ---------------- init: zero cnt + reduction scratch (replaces 3 memsets) ----------------

__global__ __launch_bounds__(256) void init_kernel(int* __restrict__ cnt,
                                                   float* __restrict__ red6,
                                                   float* __restrict__ red7,
                                                   int* __restrict__ ctrs) {
    int i = blockIdx.x * blockDim.x + threadIdx.x;
    if (i < N_NODES) cnt[i] = 0;
    if (i < 256) { red6[i] = 0.0f; red7[i] = 0.0f; }
    if (i == 0) { ctrs[0] = 0; ctrs[1] = 0; }
}

// ---------------- CSR build ----------------

__global__ void count_kernel(const int* __restrict__ rows, int* __restrict__ cnt) {
    int e = blockIdx.x * blockDim.x + threadIdx.x;
    if (e < N_EDGES) atomicAdd(&cnt[rows[e]], 1);
}

__global__ __launch_bounds__(1024) void scan_kernel(const int* __restrict__ cnt,
                                                    int* __restrict__ row_start,
                                                    int* __restrict__ cursor) {
    __shared__ int part[1024];
    const int t = threadIdx.x;
    const int CH = (N_NODES + 1023) / 1024;  // 20
    int lo = t * CH, hi = min(lo + CH, N_NODES);
    int s = 0;
    for (int i = lo; i < hi; ++i) s += cnt[i];
    part[t] = s;
    __syncthreads();
    for (int off = 1; off < 1024; off <<= 1) {
        int v = (t >= off) ? part[t - off] : 0;
        __syncthreads();
        if (t >= off) part[t] += v;
        __syncthreads();
    }
    int run = (t > 0) ? part[t - 1] : 0;
    for (int i = lo; i < hi; ++i) {
        row_start[i] = run;
        cursor[i] = run;
        run += cnt[i];
    }
    if (t == 1023) row_start[N_NODES] = part[1023];
}

__global__ void scatter_kernel(const int* __restrict__ rows, const int* __restrict__ cols,
                               const float* __restrict__ vals, int* __restrict__ cursor,
                               float2* __restrict__ epack) {
    int e = blockIdx.x * blockDim.x + threadIdx.x;
    if (e >= N_EDGES) return;
    int r = rows[e];
    int p = atomicAdd(&cursor[r], 1);
    epack[p] = make_float2(vals[e], __int_as_float(cols[e]));
}

// ---------------- f(z) = LayerNorm(K*z + A z) ----------------
// One wave per row, split into two 32-lane halves; each half gathers a
// different edge's z-row at 16 B/lane (float4). XCD-affine swizzle:
// graph = blockIdx.x % 8 == XCD id, so each XCD's L2 caches exactly one
// graph's 1.28 MB z-slab -> gathers are L2-hot.

__global__ __launch_bounds__(256) void feval_kernel(const float* __restrict__ z,
                                                    const float* __restrict__ Kd,
                                                    const float* __restrict__ lnw,
                                                    const float* __restrict__ lnb,
                                                    const int* __restrict__ row_start,
                                                    const float2* __restrict__ epack,
                                                    float* __restrict__ out) {
    // 5000 blocks = 625 per graph x 8 graphs; 4 waves (rows) per block
    int b = blockIdx.x;
    int g = b & 7;              // graph == XCD (round-robin dispatch heuristic)
    int q = b >> 3;             // local block index within graph [0,625)
    int wave = threadIdx.x >> 6;
    int r = g * NPG + q * 4 + wave;

    int lane = threadIdx.x & 63;
    int p = lane >> 5;          // half index: which edge of a pair
    int l = lane & 31;
    int d0 = l * 4;             // each half-lane owns 4 consecutive dims

    float4 acc = make_float4(0.f, 0.f, 0.f, 0.f);
    if (p == 0) {
        float4 zv = *(const float4*)(z + (size_t)r * DD + d0);
        float k = Kd[r];
        acc = make_float4(k * zv.x, k * zv.y, k * zv.z, k * zv.w);
    }

    int e0 = row_start[r], ne = row_start[r + 1] - e0;
    int i = p;
    for (; i + 2 < ne; i += 4) {
        float2 ea = epack[e0 + i];
        float2 eb = epack[e0 + i + 2];
        float4 za = *(const float4*)(z + (size_t)__float_as_int(ea.y) * DD + d0);
        float4 zb = *(const float4*)(z + (size_t)__float_as_int(eb.y) * DD + d0);
        acc.x = fmaf(ea.x, za.x, acc.x); acc.y = fmaf(ea.x, za.y, acc.y);
        acc.z = fmaf(ea.x, za.z, acc.z); acc.w = fmaf(ea.x, za.w, acc.w);
        acc.x = fmaf(eb.x, zb.x, acc.x); acc.y = fmaf(eb.x, zb.y, acc.y);
        acc.z = fmaf(eb.x, zb.z, acc.z); acc.w = fmaf(eb.x, zb.w, acc.w);
    }
    if (i < ne) {
        float2 ea = epack[e0 + i];
        float4 za = *(const float4*)(z + (size_t)__float_as_int(ea.y) * DD + d0);
        acc.x = fmaf(ea.x, za.x, acc.x); acc.y = fmaf(ea.x, za.y, acc.y);
        acc.z = fmaf(ea.x, za.z, acc.z); acc.w = fmaf(ea.x, za.w, acc.w);
    }

    // combine the two halves (lane l and l+32 hold the same dims)
    acc.x += __shfl_xor(acc.x, 32, 64);
    acc.y += __shfl_xor(acc.y, 32, 64);
    acc.z += __shfl_xor(acc.z, 32, 64);
    acc.w += __shfl_xor(acc.w, 32, 64);

    // LayerNorm stats over 128 dims = 32 lanes x 4 (both halves identical)
    float s = acc.x + acc.y + acc.z + acc.w;
    float sq = acc.x * acc.x + acc.y * acc.y + acc.z * acc.z + acc.w * acc.w;
#pragma unroll
    for (int off = 16; off; off >>= 1) {
        s += __shfl_xor(s, off, 64);
        sq += __shfl_xor(sq, off, 64);
    }
    float mu = s * (1.0f / DD);
    float var = sq * (1.0f / DD) - mu * mu;
    float rstd = rsqrtf(var + 1e-5f);

    if (p == 0) {
        float4 wv = *(const float4*)(lnw + d0);
        float4 bv = *(const float4*)(lnb + d0);
        float4 ov;
        ov.x = wv.x * (acc.x - mu) * rstd + bv.x;
        ov.y = wv.y * (acc.y - mu) * rstd + bv.y;
        ov.z = wv.z * (acc.z - mu) * rstd + bv.z;
        ov.w = wv.w * (acc.w - mu) * rstd + bv.w;
        *(float4*)(out + (size_t)r * DD + d0) = ov;
    }
}

// ---------------- Anderson reduction + fused last-block 4x4 solve ----------------

struct Cols10 { const float* f[5]; const float* z[5]; };
struct Cols5  { const float* f[5]; };

__device__ __forceinline__ float dot4(float4 a, float4 b) {
    return a.x * b.x + a.y * b.y + a.z * b.z + a.w * b.w;
}
__device__ __forceinline__ float4 sub4(float4 a, float4 b) {
    return make_float4(a.x - b.x, a.y - b.y, a.z - b.z, a.w - b.w);
}

#define RED_T 160000
__global__ __launch_bounds__(256) void reduce_kernel(Cols10 cols, float* __restrict__ red,
                                                     int* __restrict__ ctr,
                                                     float* __restrict__ gam) {
    int tid = blockIdx.x * 256 + threadIdx.x;
    float acc[14];
#pragma unroll
    for (int k = 0; k < 14; ++k) acc[k] = 0.f;

#pragma unroll
    for (int ph = 0; ph < 2; ++ph) {
        int ja = tid + (2 * ph) * RED_T;
        int jb = ja + RED_T;
        float4 fa[5], za[5], fb[5], zb[5];
#pragma unroll
        for (int c = 0; c < 5; ++c) {
            fa[c] = ((const float4*)cols.f[c])[ja];
            za[c] = ((const float4*)cols.z[c])[ja];
            fb[c] = ((const float4*)cols.f[c])[jb];
            zb[c] = ((const float4*)cols.z[c])[jb];
        }
        float4 Ga[5], Gb[5];
#pragma unroll
        for (int c = 0; c < 5; ++c) { Ga[c] = sub4(fa[c], za[c]); Gb[c] = sub4(fb[c], zb[c]); }
        float4 dga[4], dgb[4];
#pragma unroll
        for (int a = 0; a < 4; ++a) { dga[a] = sub4(Ga[a + 1], Ga[a]); dgb[a] = sub4(Gb[a + 1], Gb[a]); }
        int k = 0;
#pragma unroll
        for (int a = 0; a < 4; ++a)
#pragma unroll
            for (int b = a; b < 4; ++b) { acc[k] += dot4(dga[a], dga[b]) + dot4(dgb[a], dgb[b]); ++k; }
#pragma unroll
        for (int a = 0; a < 4; ++a) acc[10 + a] += dot4(dga[a], Ga[4]) + dot4(dgb[a], Gb[4]);
    }

#pragma unroll
    for (int off = 32; off; off >>= 1)
#pragma unroll
        for (int k = 0; k < 14; ++k) acc[k] += __shfl_xor(acc[k], off, 64);

    __shared__ float sh[4][14];
    int wave = threadIdx.x >> 6, lane = threadIdx.x & 63;
    if (lane == 0)
#pragma unroll
        for (int k = 0; k < 14; ++k) sh[wave][k] = acc[k];
    __syncthreads();
    if (threadIdx.x < 14) {
        int k = threadIdx.x;
        atomicAdd(&red[k * 16], sh[0][k] + sh[1][k] + sh[2][k] + sh[3][k]);  // padded lines
    }
    __syncthreads();

    if (threadIdx.x == 0) {
        __threadfence();
        int old = __hip_atomic_fetch_add(ctr, 1, __ATOMIC_ACQ_REL, __HIP_MEMORY_SCOPE_AGENT);
        if (old == RED_BLOCKS - 1) {
            // last block: all atomics visible; solve H gamma = rhs
            __threadfence();
            float A[4][4], b[4];
            float v[14];
            for (int k = 0; k < 14; ++k)
                v[k] = __hip_atomic_load(&red[k * 16], __ATOMIC_RELAXED, __HIP_MEMORY_SCOPE_AGENT);
            int k = 0;
            for (int a = 0; a < 4; ++a)
                for (int c = a; c < 4; ++c) { A[a][c] = v[k]; A[c][a] = v[k]; ++k; }
            for (int a = 0; a < 4; ++a) A[a][a] += 0.1f;
            for (int a = 0; a < 4; ++a) b[a] = v[10 + a];

            for (int col = 0; col < 4; ++col) {
                int piv = col;
                float best = fabsf(A[col][col]);
                for (int rr = col + 1; rr < 4; ++rr) {
                    float m = fabsf(A[rr][col]);
                    if (m > best) { best = m; piv = rr; }
                }
                if (piv != col) {
                    for (int c2 = 0; c2 < 4; ++c2) { float t = A[col][c2]; A[col][c2] = A[piv][c2]; A[piv][c2] = t; }
                    float t = b[col]; b[col] = b[piv]; b[piv] = t;
                }
                float inv = 1.0f / A[col][col];
                for (int rr = col + 1; rr < 4; ++rr) {
                    float m = A[rr][col] * inv;
                    for (int c2 = col; c2 < 4; ++c2) A[rr][c2] -= m * A[col][c2];
                    b[rr] -= m * b[col];
                }
            }
            float g[4];
            for (int rr = 3; rr >= 0; --rr) {
                float s2 = b[rr];
                for (int c2 = rr + 1; c2 < 4; ++c2) s2 -= A[rr][c2] * g[c2];
                g[rr] = s2 / A[rr][rr];
            }
            bool fin = isfinite(g[0]) && isfinite(g[1]) && isfinite(g[2]) && isfinite(g[3]);
            gam[0] = g[0]; gam[1] = g[1]; gam[2] = g[2]; gam[3] = g[3];
            gam[4] = fin ? 1.0f : 0.0f;
        }
    }
}

// z = 0.5*f + 0.5*(f - dF*gamma) = f - 0.5*dF*gamma   (or f if gamma non-finite)
__global__ __launch_bounds__(256) void update_kernel(Cols5 c, const float* __restrict__ gam,
                                                     float* __restrict__ zout) {
    int j = blockIdx.x * blockDim.x + threadIdx.x;
    if (j >= ND4) return;
    float g0 = gam[0], g1 = gam[1], g2 = gam[2], g3 = gam[3], flag = gam[4];
    float4 f0 = ((const float4*)c.f[0])[j];
    float4 f1 = ((const float4*)c.f[1])[j];
    float4 f2 = ((const float4*)c.f[2])[j];
    float4 f3 = ((const float4*)c.f[3])[j];
    float4 f4 = ((const float4*)c.f[4])[j];
    float4 o;
    if (flag != 0.0f) {
        o.x = f4.x - 0.5f * ((f1.x - f0.x) * g0 + (f2.x - f1.x) * g1 + (f3.x - f2.x) * g2 + (f4.x - f3.x) * g3);
        o.y = f4.y - 0.5f * ((f1.y - f0.y) * g0 + (f2.y - f1.y) * g1 + (f3.y - f2.y) * g2 + (f4.y - f3.y) * g3);
        o.z = f4.z - 0.5f * ((f1.z - f0.z) * g0 + (f2.z - f1.z) * g1 + (f3.z - f2.z) * g2 + (f4.z - f3.z) * g3);
        o.w = f4.w - 0.5f * ((f1.w - f0.w) * g0 + (f2.w - f1.w) * g1 + (f3.w - f2.w) * g2 + (f4.w - f3.w) * g3);
    } else {
        o = f4;
    }
    ((float4*)zout)[j] = o;
}

// ---------------- host ----------------

extern "C" void kernel_launch(void* const* d_in, const int* in_sizes, int n_in,
                              void* d_out, int out_size, void* d_ws, size_t ws_size,
                              hipStream_t stream) {
    const float* x_init = (const float*)d_in[0];
    const float* Kd     = (const float*)d_in[1];
    const float* vals   = (const float*)d_in[2];
    const float* lnw    = (const float*)d_in[3];
    const float* lnb    = (const float*)d_in[4];
    const int*   rows   = (const int*)d_in[5];
    const int*   cols   = (const int*)d_in[6];
    float* out = (float*)d_out;

    char* p = (char*)d_ws;
    auto carve = [&](size_t bytes) -> void* {
        void* r = (void*)p;
        p += (bytes + 255) & ~(size_t)255;
        return r;
    };
    float*  Fh        = (float*)carve((size_t)6 * ND * 4);   // rolling f_t history, slot t%6
    float*  red6      = (float*)carve(1024);                 // 14 counters, stride-16 floats
    float*  red7      = (float*)carve(1024);
    float*  gam6      = (float*)carve(256);
    float*  gam7      = (float*)carve(256);
    int*    ctrs      = (int*)carve(256);
    int*    row_start = (int*)carve((N_NODES + 1) * 4);
    int*    cursor    = (int*)carve(N_NODES * 4);
    int*    cnt       = (int*)carve(N_NODES * 4);
    float2* epack     = (float2*)carve((size_t)N_EDGES * 8);
    float*  zA        = out;  // d_out doubles as storage for Anderson z7 (overwritten at t=7)

    // init + CSR build (once per launch, reused by all 8 iterations)
    init_kernel<<<(N_NODES + 255) / 256, 256, 0, stream>>>(cnt, red6, red7, ctrs);
    count_kernel<<<(N_EDGES + 255) / 256, 256, 0, stream>>>(rows, cnt);
    scan_kernel<<<1, 1024, 0, stream>>>(cnt, row_start, cursor);
    scatter_kernel<<<(N_EDGES + 255) / 256, 256, 0, stream>>>(rows, cols, vals, cursor, epack);

    auto Fslot = [&](int t) -> float* { return Fh + (size_t)(t % 6) * ND; };

    for (int t = 0; t < 8; ++t) {
        const float* zsrc = (t == 0) ? x_init : (t <= 6 ? Fslot(t - 1) : zA);
        feval_kernel<<<N_NODES / 4, 256, 0, stream>>>(
            zsrc, Kd, lnw, lnb, row_start, epack, Fslot(t));

        if (t >= 6) {
            Cols10 rc;
            for (int c2 = 0; c2 < 5; ++c2) {
                int tc = t - 4 + c2;
                rc.f[c2] = Fslot(tc);
                rc.z[c2] = (tc == 7) ? (const float*)zA : (const float*)Fslot(tc - 1);
            }
            float* red = (t == 6) ? red6 : red7;
            float* gam = (t == 6) ? gam6 : gam7;
            reduce_kernel<<<RED_BLOCKS, 256, 0, stream>>>(rc, red, ctrs + (t - 6), gam);

            Cols5 uc;
            for (int c2 = 0; c2 < 5; ++c2) uc.f[c2] = Fslot(t - 4 + c2);
            float* zdst = (t == 6) ? zA : out;
            update_kernel<<<(ND4 + 255) / 256, 256, 0, stream>>>(uc, gam, zdst);
        }
    }
}